// Round 23
// baseline (59.134 us; speedup 1.0000x reference)
//
#include <hip/hip_runtime.h>
#include <hip/hip_bf16.h>
#include <math.h>

namespace {
constexpr int kC  = 256;   // channels
constexpr int kW  = 48;    // width
constexpr int kM  = 2304;  // tokens = 48*48
constexpr int kB  = 2;     // batch
constexpr int kDH = 32;    // head dim
constexpr int kH  = 8;     // heads
constexpr int kNT = kM / 32;   // 72 tiles of 32 tokens
constexpr int kNT16 = kM / 16; // 144 tiles of 16 tokens (conv A layout)
}

typedef float  f32x4   __attribute__((ext_vector_type(4)));
typedef float  f32x16  __attribute__((ext_vector_type(16)));
typedef __bf16 bf16x8  __attribute__((ext_vector_type(8)));

// 16x16x32: A row=lane&15 ; B col=lane&15 ; D col=lane&15, row=(lane>>4)*4+reg
__device__ __forceinline__ f32x4 mfma16(bf16x8 a, bf16x8 b, f32x4 c) {
    return __builtin_amdgcn_mfma_f32_16x16x32_bf16(a, b, c, 0, 0, 0);
}
// 32x32x16: A row=lane&31 ; B col=lane&31 ; D col=lane&31, row=(reg&3)+8*(reg>>2)+4*(lane>>5)
__device__ __forceinline__ f32x16 mfma32(bf16x8 a, bf16x8 b, f32x16 c) {
    return __builtin_amdgcn_mfma_f32_32x32x16_bf16(a, b, c, 0, 0, 0);
}
__device__ __forceinline__ float hexp2(float x) { return __builtin_amdgcn_exp2f(x); }

// Fragment-order layouts (r22): rows-of-16 x 8ch chunks:
//   T[tile16][chunk(ch/8)][lane(row&15)][8ch]  (128B per (tile,chunk,lane-row) slab)
// -> every conv MFMA operand load group covers a contiguous 1KB slab.
// Attention tiles keep the r14 [b][h][tile32][row32][ch32] layout.

// ---- merged prep: weight pack tiled (0-255) + PE (256-303) + xn^T tiled ---
__global__ __launch_bounds__(256) void prep_kernel(
    const float* __restrict__ x,
    const float* __restrict__ gamma, const float* __restrict__ beta,
    const float* __restrict__ rmean, const float* __restrict__ rvar,
    const float* __restrict__ w0, const float* __restrict__ w1,
    const float* __restrict__ w2, const float* __restrict__ w3,
    float* __restrict__ PEt,
    __hip_bfloat16* __restrict__ o0, __hip_bfloat16* __restrict__ o1,
    __hip_bfloat16* __restrict__ o2, __hip_bfloat16* __restrict__ o3,
    __hip_bfloat16* __restrict__ Xnt) {
    __shared__ float T[64][65];
    __shared__ float bni[64], bns[64];
    int bid = blockIdx.x, t = threadIdx.x;
    if (bid < 256) {            // weight pack -> fragment-order tiled
        int wi = bid >> 6;
        const float* w = wi == 0 ? w0 : wi == 1 ? w1 : wi == 2 ? w2 : w3;
        __hip_bfloat16* o = wi == 0 ? o0 : wi == 1 ? o1 : wi == 2 ? o2 : o3;
        int idx = ((bid & 63) * 256 + t) * 4;   // 4 consecutive ch of one row
        int row = idx >> 8, ch = idx & 255;     // ch % 4 == 0
        float4 v = *reinterpret_cast<const float4*>(w + idx);
        __hip_bfloat16 hv[4] = {__float2bfloat16(v.x), __float2bfloat16(v.y),
                                __float2bfloat16(v.z), __float2bfloat16(v.w)};
        int ta = ((row >> 4) * 32 + (ch >> 3)) * 128 + (row & 15) * 8 + (ch & 7);
        *reinterpret_cast<uint2*>(o + ta) = *reinterpret_cast<uint2*>(hv);
    } else if (bid < 304) {     // PE table [pos][c], pos = bid-256 (48 blocks)
        int pos = bid - 256;
        int cc = (t < 128) ? t : (t - 128);
        float dv = __expf((float)(cc & ~1) * (float)(-9.210340371976184 / 128.0));
        float pd = (float)pos * dv;
        float rv = (t & 1) ? cosf(pd) : sinf(pd);
        const float RINV = 1.0f / sqrtf(128.0f + 1e-6f);
        PEt[pos * 256 + t] = rv * RINV;
    } else {                    // xn^T tiled: id in [0,288) -> (mb 36, cb 4, b 2)
        int id = bid - 304;
        int mb = id % 36, rest = id / 36;
        int cb = rest & 3, b = rest >> 2;
        int m0 = mb * 64, c0 = cb * 64;
        if (t < 64) {
            float iv = gamma[c0 + t] / sqrtf(rvar[c0 + t] + 1e-5f);
            bni[t] = iv;
            bns[t] = beta[c0 + t] - rmean[c0 + t] * iv;
        }
        __syncthreads();
        int ml = t & 63;
        #pragma unroll
        for (int i = 0; i < 16; i++) {
            int c = (t >> 6) + i * 4;
            T[c][ml] = x[(size_t)(b * kC + c0 + c) * kM + m0 + ml] * bni[c] + bns[c];
        }
        __syncthreads();
        int mr = t >> 2, cseg = (t & 3) * 16;   // token m0+mr, ch c0+cseg..+15
        __hip_bfloat16 v[16];
        #pragma unroll
        for (int j = 0; j < 16; j++) v[j] = __float2bfloat16(T[cseg + j][mr]);
        // tiled write: tile=(m0+mr)/16, chunks (c0+cseg)/8 and +1, lane=(m0+mr)&15
        int mt16 = (m0 + mr) >> 4, lr = mr & 15, ch8 = (c0 + cseg) >> 3;
        __hip_bfloat16* dst = Xnt + (((size_t)(b * kNT16 + mt16) * 32 + ch8) * 16 + lr) * 8;
        *reinterpret_cast<bf16x8*>(dst)       = *reinterpret_cast<bf16x8*>(&v[0]);
        *reinterpret_cast<bf16x8*>(dst + 128) = *reinterpret_cast<bf16x8*>(&v[8]);
    }
}

// ---- fused-BN 1x1 convs, 3 matrices PER BLOCK, dense fragment loads ------
__global__ __launch_bounds__(64) void conv_gemm(const __hip_bfloat16* __restrict__ Xnt,
                                                const __hip_bfloat16* __restrict__ Wv,
                                                const __hip_bfloat16* __restrict__ Wz,
                                                const __hip_bfloat16* __restrict__ Wq,
                                                __hip_bfloat16* __restrict__ Vt,
                                                __hip_bfloat16* __restrict__ Zb16,
                                                __hip_bfloat16* __restrict__ Qtt) {
    int t = threadIdx.x, li = t & 15, g = t >> 4;
    int m0 = blockIdx.x * 16, o0 = blockIdx.y * 64;
    int b = blockIdx.z;

    // A: dense tiled loads — chunk = g + 4*kb, lane-row = li
    bf16x8 a[8];
    const __hip_bfloat16* ap = Xnt + (((size_t)(b * kNT16 + (m0 >> 4)) * 32 + g) * 16 + li) * 8;
    #pragma unroll
    for (int kb = 0; kb < 8; kb++) a[kb] = *reinterpret_cast<const bf16x8*>(ap + kb * 512);

    const int mt = m0 >> 5;            // 32-token tile index
    const int mmb = m0 & 31;           // row offset within 32-tile

    // W tiled: base for (otile=o0/16, chunk=g, lane=li); + ot*4096 + kb*512
    const size_t wb = (((size_t)(o0 >> 4) * 32 + g) * 16 + li) * 8;

    // ---- V ----
    {
        f32x4 acc[4] = {{0,0,0,0},{0,0,0,0},{0,0,0,0},{0,0,0,0}};
        const __hip_bfloat16* wp = Wv + wb;
        #pragma unroll
        for (int kb = 0; kb < 8; kb++)
            #pragma unroll
            for (int ot = 0; ot < 4; ot++) {
                bf16x8 bw = *reinterpret_cast<const bf16x8*>(wp + ot * 4096 + kb * 512);
                acc[ot] = mfma16(a[kb], bw, acc[ot]);
            }
        const float SCALE2 = 0.25501988169885635f;   // (1/sqrt32)*log2e
        #pragma unroll
        for (int ot = 0; ot < 4; ot++) {
            int o = o0 + ot * 16 + li, hh = o >> 5, cc = o & 31;
            __hip_bfloat16* base = Vt + (((size_t)(b * kH + hh) * kNT + mt) * 32) * 32 + cc;
            #pragma unroll
            for (int r = 0; r < 4; r++)
                base[(mmb + 4 * g + r) * 32] = __float2bfloat16(acc[ot][r] * SCALE2);
        }
    }
    // ---- Z ----
    {
        f32x4 acc[4] = {{0,0,0,0},{0,0,0,0},{0,0,0,0},{0,0,0,0}};
        const __hip_bfloat16* wp = Wz + wb;
        #pragma unroll
        for (int kb = 0; kb < 8; kb++)
            #pragma unroll
            for (int ot = 0; ot < 4; ot++) {
                bf16x8 bw = *reinterpret_cast<const bf16x8*>(wp + ot * 4096 + kb * 512);
                acc[ot] = mfma16(a[kb], bw, acc[ot]);
            }
        #pragma unroll
        for (int ot = 0; ot < 4; ot++)
            #pragma unroll
            for (int r = 0; r < 4; r++)
                Zb16[(size_t)(b * kM + m0 + 4 * g + r) * kC + o0 + ot * 16 + li] = __float2bfloat16(acc[ot][r]);
    }
    // ---- Q ----
    {
        f32x4 acc[4] = {{0,0,0,0},{0,0,0,0},{0,0,0,0},{0,0,0,0}};
        const __hip_bfloat16* wp = Wq + wb;
        #pragma unroll
        for (int kb = 0; kb < 8; kb++)
            #pragma unroll
            for (int ot = 0; ot < 4; ot++) {
                bf16x8 bw = *reinterpret_cast<const bf16x8*>(wp + ot * 4096 + kb * 512);
                acc[ot] = mfma16(a[kb], bw, acc[ot]);
            }
        #pragma unroll
        for (int ot = 0; ot < 4; ot++) {
            int o = o0 + ot * 16 + li, hh = o >> 5, d = o & 31;
            __hip_bfloat16* base = Qtt + (((size_t)(b * kH + hh) * kNT + mt) * 32 + d) * 32 + mmb + 4 * g;
            *reinterpret_cast<__hip_bfloat162*>(base) =
                __float22bfloat162_rn(make_float2(acc[ot][0], acc[ot][1]));
            *reinterpret_cast<__hip_bfloat162*>(base + 2) =
                __float22bfloat162_rn(make_float2(acc[ot][2], acc[ot][3]));
        }
    }
}

// ---- zr = l2n(z) + l2n(r): 4 tokens/block, 1 wave/token -> ZRt tiled -----
__global__ __launch_bounds__(256) void zr_kernel(const __hip_bfloat16* __restrict__ Z,
                                                 const float* __restrict__ PEt,
                                                 __hip_bfloat16* __restrict__ ZRt) {
    int t = threadIdx.x;
    int bm = blockIdx.x * 4 + (t >> 6);   // token
    int lane = t & 63;                     // 4 channels each
    int m = bm % kM, b = bm / kM;
    union { uint2 u; __hip_bfloat16 h[4]; } zu;
    zu.u = *reinterpret_cast<const uint2*>(Z + (size_t)bm * kC + lane * 4);
    float z[4];
    #pragma unroll
    for (int j = 0; j < 4; j++) z[j] = __bfloat162float(zu.h[j]);
    float ss = (z[0]*z[0] + z[1]*z[1]) + (z[2]*z[2] + z[3]*z[3]);
    #pragma unroll
    for (int k = 32; k >= 1; k >>= 1) ss += __shfl_xor(ss, k);
    float zinv = 1.0f / sqrtf(ss + 1e-6f);
    int pos = (lane < 32) ? (m % kW) : (m / kW);
    f32x4 pe = *reinterpret_cast<const f32x4*>(PEt + pos * 256 + lane * 4);
    union { uint2 u; __hip_bfloat16 h[4]; } ou;
    #pragma unroll
    for (int j = 0; j < 4; j++) ou.h[j] = __float2bfloat16(z[j] * zinv + pe[j]);
    int hh = lane >> 3, cc = (lane * 4) & 31;
    *reinterpret_cast<uint2*>(
        ZRt + (((size_t)(b * kH + hh) * kNT + (m >> 5)) * 32 + (m & 31)) * 32 + cc) = ou.u;
}

// ---- fused flash attention, q-tile-PAIR per block + s_setprio (T5) -------
// Grid 576: bh = blk & 15 (XCD-local per bh since blk = bh mod 16), pair = blk>>4.
// 8 waves each own 9 KV tiles, compute BOTH q-tiles from one za/qa load.
// Waves run barrier-free at independent phases -> setprio(1) around MFMA
// clusters lets MFMA-entering waves win issue arbitration (m191 regime).
// PV B-frag via cvt_pk + v_permlane32_swap (vdst.hi <-> vsrc.lo, r10/r11).
// No max-tracking (|logit*log2e| <~ 33; exp2 fp32-safe). Epilogue LDS combine x2.
// Y written TILED (b,h,tile,row32,dh32) -> conv_out reads dense slabs.
__global__ __launch_bounds__(512) void flash_attn_fused(
    const __hip_bfloat16* __restrict__ Vt,   // (B,H,72,32m,32c) prescaled
    const __hip_bfloat16* __restrict__ ZRt,  // (B,H,72,32n,32c)
    const __hip_bfloat16* __restrict__ Qtt,  // (B,H,72,32d,32n)
    __hip_bfloat16* __restrict__ Yt)         // (B,H,72,32m,32d) tiled
{
    __shared__ float Aw[8][32 * 36];   // per-wave Y^T partial, [m][dh] pitch 36
    __shared__ float Ls[8][64];        // per-wave per-lane lsum partials
    const int t = threadIdx.x;
    const int w = t >> 6, lane = t & 63;
    const int c = lane & 31, hi = lane >> 5;
    const int blk = blockIdx.x;
    const int bh = blk & 15, pair = blk >> 4;
    const int b = bh >> 3, h = bh & 7;
    const f32x16 zero16 = {0,0,0,0,0,0,0,0,0,0,0,0,0,0,0,0};

    const int lo = c * 32 + hi * 8;    // lane offset within a 1024-elem tile
    const size_t hb = (size_t)bh * kNT;

    // V fragments for both q-tiles of the pair
    bf16x8 vf[2][2];
    #pragma unroll
    for (int mt = 0; mt < 2; mt++) {
        const __hip_bfloat16* vb = Vt + (hb + pair * 2 + mt) * 1024 + lo;
        vf[mt][0] = *reinterpret_cast<const bf16x8*>(vb);
        vf[mt][1] = *reinterpret_cast<const bf16x8*>(vb + 16);
    }

    const __hip_bfloat16* zb = ZRt + (hb + w * 9) * 1024 + lo;   // walk +1024/iter
    const __hip_bfloat16* qb = Qtt + (hb + w * 9) * 1024 + lo;

    f32x16 acc[2] = {zero16, zero16};
    float lsum[2] = {0.f, 0.f};

    bf16x8 za0 = *reinterpret_cast<const bf16x8*>(zb);
    bf16x8 za1 = *reinterpret_cast<const bf16x8*>(zb + 16);
    bf16x8 qa0 = *reinterpret_cast<const bf16x8*>(qb);
    bf16x8 qa1 = *reinterpret_cast<const bf16x8*>(qb + 16);

    for (int it = 0; it < 9; ++it) {
        const int nx = (it < 8) ? (it + 1) * 1024 : 0;   // harmless wrap

        // prefetch next tile's fragments (contiguous 2KB slabs)
        bf16x8 za0n = *reinterpret_cast<const bf16x8*>(zb + nx);
        bf16x8 za1n = *reinterpret_cast<const bf16x8*>(zb + nx + 16);
        bf16x8 qa0n = *reinterpret_cast<const bf16x8*>(qb + nx);
        bf16x8 qa1n = *reinterpret_cast<const bf16x8*>(qb + nx + 16);

        #pragma unroll
        for (int mt = 0; mt < 2; mt++) {
            // QK^T for q-tile mt (KV regs shared across mt)
            __builtin_amdgcn_s_setprio(1);
            f32x16 st = mfma32(za0, vf[mt][0], zero16);
            st = mfma32(za1, vf[mt][1], st);
            __builtin_amdgcn_s_setprio(0);

            // raw exp2 (no max subtraction), tree sum
            float p[16];
            #pragma unroll
            for (int r = 0; r < 16; r++) p[r] = hexp2(st[r]);
            float s01 = (p[0] + p[1]) + (p[2] + p[3]);
            float s23 = (p[4] + p[5]) + (p[6] + p[7]);
            float s45 = (p[8] + p[9]) + (p[10] + p[11]);
            float s67 = (p[12] + p[13]) + (p[14] + p[15]);
            lsum[mt] += (s01 + s23) + (s45 + s67);

            // PV: two K=16 MFMAs; B-frags via cvt_pk + permlane32_swap
            __builtin_amdgcn_s_setprio(1);
            #pragma unroll
            for (int kk = 0; kk < 2; kk++) {
                __hip_bfloat162 xw0 = __float22bfloat162_rn(make_float2(p[8*kk+0], p[8*kk+1]));
                __hip_bfloat162 xw1 = __float22bfloat162_rn(make_float2(p[8*kk+2], p[8*kk+3]));
                __hip_bfloat162 yw0 = __float22bfloat162_rn(make_float2(p[8*kk+4], p[8*kk+5]));
                __hip_bfloat162 yw1 = __float22bfloat162_rn(make_float2(p[8*kk+6], p[8*kk+7]));
                unsigned x0 = *reinterpret_cast<unsigned*>(&xw0);
                unsigned x1 = *reinterpret_cast<unsigned*>(&xw1);
                unsigned y0 = *reinterpret_cast<unsigned*>(&yw0);
                unsigned y1 = *reinterpret_cast<unsigned*>(&yw1);
                // vdst.hi <-> vsrc.lo: hi=0: {own x, partner x}; hi=1: {partner y, own y}
                asm("v_permlane32_swap_b32 %0, %1" : "+v"(x0), "+v"(y0));
                asm("v_permlane32_swap_b32 %0, %1" : "+v"(x1), "+v"(y1));
                union { unsigned u[4]; bf16x8 v; } bf;
                bf.u[0] = x0; bf.u[1] = x1; bf.u[2] = y0; bf.u[3] = y1;
                acc[mt] = mfma32(kk == 0 ? qa0 : qa1, bf.v, acc[mt]);
            }
            __builtin_amdgcn_s_setprio(0);
        }

        za0 = za0n; za1 = za1n; qa0 = qa0n; qa1 = qa1n;
    }

    // epilogue: for each q-tile, stage partials + combine across the 8 waves
    #pragma unroll
    for (int mt = 0; mt < 2; mt++) {
        #pragma unroll
        for (int r = 0; r < 16; r++) {
            int dh = (r & 3) + 8 * (r >> 2) + 4 * hi;
            Aw[w][c * 36 + dh] = acc[mt][r];
        }
        Ls[w][lane] = lsum[mt];
        __syncthreads();

        if (t < 256) {   // 32 m-rows x 8 dh-groups of 4
            const int m = t & 31, dh0 = (t >> 5) * 4;
            float L = 0.f;
            #pragma unroll
            for (int w2 = 0; w2 < 8; w2++) L += Ls[w2][m] + Ls[w2][m + 32];
            f32x4 s4 = {0.f, 0.f, 0.f, 0.f};
            #pragma unroll
            for (int w2 = 0; w2 < 8; w2++)
                s4 = s4 + *reinterpret_cast<const f32x4*>(&Aw[w2][m * 36 + dh0]);
            float inv = 1.0f / L;
            union { uint2 u2; __hip_bfloat162 h2[2]; } o;
            o.h2[0] = __float22bfloat162_rn(make_float2(s4[0] * inv, s4[1] * inv));
            o.h2[1] = __float22bfloat162_rn(make_float2(s4[2] * inv, s4[3] * inv));
            // tiled write: Yt[b][h][tile=pair*2+mt][m][dh0..dh0+3]
            *reinterpret_cast<uint2*>(
                Yt + ((hb + pair * 2 + mt) * 32 + m) * 32 + dh0) = o.u2;
        }
        __syncthreads();   // WAR: next mt's staging must not race this combine
    }
}

// ---- output conv: dense Yt A-reads + dense tiled Wo B-reads ---------------
__global__ __launch_bounds__(64) void conv_out_gemm(const __hip_bfloat16* __restrict__ Yt,
                                                    const __hip_bfloat16* __restrict__ Wo,
                                                    float* __restrict__ out) {
    int t = threadIdx.x, li = t & 15, g = t >> 4;
    int m0 = blockIdx.x * 16, o0 = blockIdx.y * 64, b = blockIdx.z;
    const int mt = m0 >> 5, mmb = m0 & 31;

    bf16x8 a[8];
    #pragma unroll
    for (int kb = 0; kb < 8; kb++)
        a[kb] = *reinterpret_cast<const bf16x8*>(
            Yt + (((size_t)(b * kH + kb) * kNT + mt) * 32 + mmb + li) * 32 + g * 8);

    f32x4 acc[4] = {{0,0,0,0},{0,0,0,0},{0,0,0,0},{0,0,0,0}};
    const __hip_bfloat16* wp = Wo + (((size_t)(o0 >> 4) * 32 + g) * 16 + li) * 8;
    #pragma unroll
    for (int kb = 0; kb < 8; kb++) {
        #pragma unroll
        for (int ot = 0; ot < 4; ot++) {
            bf16x8 bw = *reinterpret_cast<const bf16x8*>(wp + ot * 4096 + kb * 512);
            acc[ot] = mfma16(a[kb], bw, acc[ot]);
        }
    }
    #pragma unroll
    for (int ot = 0; ot < 4; ot++) {
        int o = o0 + ot * 16 + li;
        *reinterpret_cast<f32x4*>(out + (size_t)(b * kC + o) * kM + m0 + 4 * g) = acc[ot];
    }
}

extern "C" void kernel_launch(void* const* d_in, const int* in_sizes, int n_in,
                              void* d_out, int out_size, void* d_ws, size_t ws_size,
                              hipStream_t stream) {
    const float* x     = (const float*)d_in[0];
    const float* gamma = (const float*)d_in[1];
    const float* beta  = (const float*)d_in[2];
    const float* rmean = (const float*)d_in[3];
    const float* rvar  = (const float*)d_in[4];
    const float* v_w   = (const float*)d_in[5];
    const float* z_w   = (const float*)d_in[6];
    const float* q_w   = (const float*)d_in[7];
    const float* o_w   = (const float*)d_in[8];
    float* out = (float*)d_out;

    char* wsb = (char*)d_ws;
    const size_t BMC = (size_t)kB * kM * kC;    // 1,179,648
    float* PEt     = (float*)(wsb + 4096);      // [pos][c], 49152 B -> ends 53248
    __hip_bfloat16* Wv16 = (__hip_bfloat16*)(wsb + 53248);   // tiled fragment order
    __hip_bfloat16* Wz16 = Wv16 + 65536;
    __hip_bfloat16* Wq16 = Wz16 + 65536;
    __hip_bfloat16* Wo16 = Wq16 + 65536;
    __hip_bfloat16* Xnt  = Wo16 + 65536;        // tiled fragment order
    __hip_bfloat16* Vt   = Xnt + BMC;           // tiled (B,H,72,32,32)
    __hip_bfloat16* Zb16 = Vt + BMC;            // (B,M,C)
    __hip_bfloat16* ZRt  = Zb16 + BMC;          // tiled
    __hip_bfloat16* Qtt  = ZRt + BMC;           // tiled
    __hip_bfloat16* Yt   = Qtt + BMC;           // tiled (B,H,72,32,32); ~14.7 MB

    prep_kernel<<<dim3(592), dim3(256), 0, stream>>>(
        x, gamma, beta, rmean, rvar, v_w, z_w, q_w, o_w,
        PEt, Wv16, Wz16, Wq16, Wo16, Xnt);
    conv_gemm<<<dim3(kM / 16, kC / 64, kB), dim3(64), 0, stream>>>(
        Xnt, Wv16, Wz16, Wq16, Vt, Zb16, Qtt);
    zr_kernel<<<dim3(kB * kM / 4), dim3(256), 0, stream>>>(Zb16, PEt, ZRt);
    flash_attn_fused<<<dim3((kNT / 2) * kH * kB), dim3(512), 0, stream>>>(Vt, ZRt, Qtt, Yt);
    conv_out_gemm<<<dim3(kM / 16, kC / 64, kB), dim3(64), 0, stream>>>(Yt, Wo16, out);
}

// Round 24
// 54.812 us; speedup vs baseline: 1.0789x; 1.0789x over previous
//
#include <hip/hip_runtime.h>
#include <hip/hip_bf16.h>
#include <math.h>

namespace {
constexpr int kC  = 256;   // channels
constexpr int kW  = 48;    // width
constexpr int kM  = 2304;  // tokens = 48*48
constexpr int kB  = 2;     // batch
constexpr int kDH = 32;    // head dim
constexpr int kH  = 8;     // heads
constexpr int kNT = kM / 32;   // 72 tiles of 32 tokens
constexpr int kNT16 = kM / 16; // 144 tiles of 16 tokens (conv A layout)
}

typedef float  f32x4   __attribute__((ext_vector_type(4)));
typedef float  f32x16  __attribute__((ext_vector_type(16)));
typedef __bf16 bf16x8  __attribute__((ext_vector_type(8)));

// 16x16x32: A row=lane&15 ; B col=lane&15 ; D col=lane&15, row=(lane>>4)*4+reg
__device__ __forceinline__ f32x4 mfma16(bf16x8 a, bf16x8 b, f32x4 c) {
    return __builtin_amdgcn_mfma_f32_16x16x32_bf16(a, b, c, 0, 0, 0);
}
// 32x32x16: A row=lane&31 ; B col=lane&31 ; D col=lane&31, row=(reg&3)+8*(reg>>2)+4*(lane>>5)
__device__ __forceinline__ f32x16 mfma32(bf16x8 a, bf16x8 b, f32x16 c) {
    return __builtin_amdgcn_mfma_f32_32x32x16_bf16(a, b, c, 0, 0, 0);
}
__device__ __forceinline__ float hexp2(float x) { return __builtin_amdgcn_exp2f(x); }

// Fragment-order layouts (r22): rows-of-16 x 8ch chunks:
//   T[tile16][chunk(ch/8)][lane(row&15)][8ch]  (128B per (tile,chunk,lane-row) slab)
// -> every conv MFMA operand load group covers a contiguous 1KB slab.
// Attention tiles keep the r14 [b][h][tile32][row32][ch32] layout.

// ---- merged prep: weight pack tiled (0-255) + PE (256-303) + xn^T tiled ---
__global__ __launch_bounds__(256) void prep_kernel(
    const float* __restrict__ x,
    const float* __restrict__ gamma, const float* __restrict__ beta,
    const float* __restrict__ rmean, const float* __restrict__ rvar,
    const float* __restrict__ w0, const float* __restrict__ w1,
    const float* __restrict__ w2, const float* __restrict__ w3,
    float* __restrict__ PEt,
    __hip_bfloat16* __restrict__ o0, __hip_bfloat16* __restrict__ o1,
    __hip_bfloat16* __restrict__ o2, __hip_bfloat16* __restrict__ o3,
    __hip_bfloat16* __restrict__ Xnt) {
    __shared__ float T[64][65];
    __shared__ float bni[64], bns[64];
    int bid = blockIdx.x, t = threadIdx.x;
    if (bid < 256) {            // weight pack -> fragment-order tiled
        int wi = bid >> 6;
        const float* w = wi == 0 ? w0 : wi == 1 ? w1 : wi == 2 ? w2 : w3;
        __hip_bfloat16* o = wi == 0 ? o0 : wi == 1 ? o1 : wi == 2 ? o2 : o3;
        int idx = ((bid & 63) * 256 + t) * 4;   // 4 consecutive ch of one row
        int row = idx >> 8, ch = idx & 255;     // ch % 4 == 0
        float4 v = *reinterpret_cast<const float4*>(w + idx);
        __hip_bfloat16 hv[4] = {__float2bfloat16(v.x), __float2bfloat16(v.y),
                                __float2bfloat16(v.z), __float2bfloat16(v.w)};
        int ta = ((row >> 4) * 32 + (ch >> 3)) * 128 + (row & 15) * 8 + (ch & 7);
        *reinterpret_cast<uint2*>(o + ta) = *reinterpret_cast<uint2*>(hv);
    } else if (bid < 304) {     // PE table [pos][c], pos = bid-256 (48 blocks)
        int pos = bid - 256;
        int cc = (t < 128) ? t : (t - 128);
        float dv = __expf((float)(cc & ~1) * (float)(-9.210340371976184 / 128.0));
        float pd = (float)pos * dv;
        float rv = (t & 1) ? cosf(pd) : sinf(pd);
        const float RINV = 1.0f / sqrtf(128.0f + 1e-6f);
        PEt[pos * 256 + t] = rv * RINV;
    } else {                    // xn^T tiled: id in [0,288) -> (mb 36, cb 4, b 2)
        int id = bid - 304;
        int mb = id % 36, rest = id / 36;
        int cb = rest & 3, b = rest >> 2;
        int m0 = mb * 64, c0 = cb * 64;
        if (t < 64) {
            float iv = gamma[c0 + t] / sqrtf(rvar[c0 + t] + 1e-5f);
            bni[t] = iv;
            bns[t] = beta[c0 + t] - rmean[c0 + t] * iv;
        }
        __syncthreads();
        int ml = t & 63;
        #pragma unroll
        for (int i = 0; i < 16; i++) {
            int c = (t >> 6) + i * 4;
            T[c][ml] = x[(size_t)(b * kC + c0 + c) * kM + m0 + ml] * bni[c] + bns[c];
        }
        __syncthreads();
        int mr = t >> 2, cseg = (t & 3) * 16;   // token m0+mr, ch c0+cseg..+15
        __hip_bfloat16 v[16];
        #pragma unroll
        for (int j = 0; j < 16; j++) v[j] = __float2bfloat16(T[cseg + j][mr]);
        // tiled write: tile=(m0+mr)/16, chunks (c0+cseg)/8 and +1, lane=(m0+mr)&15
        int mt16 = (m0 + mr) >> 4, lr = mr & 15, ch8 = (c0 + cseg) >> 3;
        __hip_bfloat16* dst = Xnt + (((size_t)(b * kNT16 + mt16) * 32 + ch8) * 16 + lr) * 8;
        *reinterpret_cast<bf16x8*>(dst)       = *reinterpret_cast<bf16x8*>(&v[0]);
        *reinterpret_cast<bf16x8*>(dst + 128) = *reinterpret_cast<bf16x8*>(&v[8]);
    }
}

// ---- fused-BN 1x1 convs, 3 matrices PER BLOCK, dense fragment loads ------
__global__ __launch_bounds__(64) void conv_gemm(const __hip_bfloat16* __restrict__ Xnt,
                                                const __hip_bfloat16* __restrict__ Wv,
                                                const __hip_bfloat16* __restrict__ Wz,
                                                const __hip_bfloat16* __restrict__ Wq,
                                                __hip_bfloat16* __restrict__ Vt,
                                                __hip_bfloat16* __restrict__ Zb16,
                                                __hip_bfloat16* __restrict__ Qtt) {
    int t = threadIdx.x, li = t & 15, g = t >> 4;
    int m0 = blockIdx.x * 16, o0 = blockIdx.y * 64;
    int b = blockIdx.z;

    // A: dense tiled loads — chunk = g + 4*kb, lane-row = li
    bf16x8 a[8];
    const __hip_bfloat16* ap = Xnt + (((size_t)(b * kNT16 + (m0 >> 4)) * 32 + g) * 16 + li) * 8;
    #pragma unroll
    for (int kb = 0; kb < 8; kb++) a[kb] = *reinterpret_cast<const bf16x8*>(ap + kb * 512);

    const int mt = m0 >> 5;            // 32-token tile index
    const int mmb = m0 & 31;           // row offset within 32-tile

    // W tiled: base for (otile=o0/16, chunk=g, lane=li); + ot*4096 + kb*512
    const size_t wb = (((size_t)(o0 >> 4) * 32 + g) * 16 + li) * 8;

    // ---- V ----
    {
        f32x4 acc[4] = {{0,0,0,0},{0,0,0,0},{0,0,0,0},{0,0,0,0}};
        const __hip_bfloat16* wp = Wv + wb;
        #pragma unroll
        for (int kb = 0; kb < 8; kb++)
            #pragma unroll
            for (int ot = 0; ot < 4; ot++) {
                bf16x8 bw = *reinterpret_cast<const bf16x8*>(wp + ot * 4096 + kb * 512);
                acc[ot] = mfma16(a[kb], bw, acc[ot]);
            }
        const float SCALE2 = 0.25501988169885635f;   // (1/sqrt32)*log2e
        #pragma unroll
        for (int ot = 0; ot < 4; ot++) {
            int o = o0 + ot * 16 + li, hh = o >> 5, cc = o & 31;
            __hip_bfloat16* base = Vt + (((size_t)(b * kH + hh) * kNT + mt) * 32) * 32 + cc;
            #pragma unroll
            for (int r = 0; r < 4; r++)
                base[(mmb + 4 * g + r) * 32] = __float2bfloat16(acc[ot][r] * SCALE2);
        }
    }
    // ---- Z ----
    {
        f32x4 acc[4] = {{0,0,0,0},{0,0,0,0},{0,0,0,0},{0,0,0,0}};
        const __hip_bfloat16* wp = Wz + wb;
        #pragma unroll
        for (int kb = 0; kb < 8; kb++)
            #pragma unroll
            for (int ot = 0; ot < 4; ot++) {
                bf16x8 bw = *reinterpret_cast<const bf16x8*>(wp + ot * 4096 + kb * 512);
                acc[ot] = mfma16(a[kb], bw, acc[ot]);
            }
        #pragma unroll
        for (int ot = 0; ot < 4; ot++)
            #pragma unroll
            for (int r = 0; r < 4; r++)
                Zb16[(size_t)(b * kM + m0 + 4 * g + r) * kC + o0 + ot * 16 + li] = __float2bfloat16(acc[ot][r]);
    }
    // ---- Q ----
    {
        f32x4 acc[4] = {{0,0,0,0},{0,0,0,0},{0,0,0,0},{0,0,0,0}};
        const __hip_bfloat16* wp = Wq + wb;
        #pragma unroll
        for (int kb = 0; kb < 8; kb++)
            #pragma unroll
            for (int ot = 0; ot < 4; ot++) {
                bf16x8 bw = *reinterpret_cast<const bf16x8*>(wp + ot * 4096 + kb * 512);
                acc[ot] = mfma16(a[kb], bw, acc[ot]);
            }
        #pragma unroll
        for (int ot = 0; ot < 4; ot++) {
            int o = o0 + ot * 16 + li, hh = o >> 5, d = o & 31;
            __hip_bfloat16* base = Qtt + (((size_t)(b * kH + hh) * kNT + mt) * 32 + d) * 32 + mmb + 4 * g;
            *reinterpret_cast<__hip_bfloat162*>(base) =
                __float22bfloat162_rn(make_float2(acc[ot][0], acc[ot][1]));
            *reinterpret_cast<__hip_bfloat162*>(base + 2) =
                __float22bfloat162_rn(make_float2(acc[ot][2], acc[ot][3]));
        }
    }
}

// ---- zr = l2n(z) + l2n(r): 4 tokens/block, 1 wave/token -> ZRt tiled -----
__global__ __launch_bounds__(256) void zr_kernel(const __hip_bfloat16* __restrict__ Z,
                                                 const float* __restrict__ PEt,
                                                 __hip_bfloat16* __restrict__ ZRt) {
    int t = threadIdx.x;
    int bm = blockIdx.x * 4 + (t >> 6);   // token
    int lane = t & 63;                     // 4 channels each
    int m = bm % kM, b = bm / kM;
    union { uint2 u; __hip_bfloat16 h[4]; } zu;
    zu.u = *reinterpret_cast<const uint2*>(Z + (size_t)bm * kC + lane * 4);
    float z[4];
    #pragma unroll
    for (int j = 0; j < 4; j++) z[j] = __bfloat162float(zu.h[j]);
    float ss = (z[0]*z[0] + z[1]*z[1]) + (z[2]*z[2] + z[3]*z[3]);
    #pragma unroll
    for (int k = 32; k >= 1; k >>= 1) ss += __shfl_xor(ss, k);
    float zinv = 1.0f / sqrtf(ss + 1e-6f);
    int pos = (lane < 32) ? (m % kW) : (m / kW);
    f32x4 pe = *reinterpret_cast<const f32x4*>(PEt + pos * 256 + lane * 4);
    union { uint2 u; __hip_bfloat16 h[4]; } ou;
    #pragma unroll
    for (int j = 0; j < 4; j++) ou.h[j] = __float2bfloat16(z[j] * zinv + pe[j]);
    int hh = lane >> 3, cc = (lane * 4) & 31;
    *reinterpret_cast<uint2*>(
        ZRt + (((size_t)(b * kH + hh) * kNT + (m >> 5)) * 32 + (m & 31)) * 32 + cc) = ou.u;
}

// ---- fused flash attention, q-tile-PAIR per block (KV L2 traffic / 2) ----
// Grid 576: bh = blk & 15 (XCD-local per bh since blk = bh mod 16), pair = blk>>4.
// 8 waves each own 9 KV tiles, compute BOTH q-tiles from one za/qa load.
// PV B-frag via cvt_pk + v_permlane32_swap (vdst.hi <-> vsrc.lo, r10/r11).
// No max-tracking (|logit*log2e| <~ 33; exp2 fp32-safe). Epilogue LDS combine x2.
// Y written TILED (b,h,tile,row32,dh32) -> conv_out reads dense slabs.
// NOTE r23: s_setprio around MFMA clusters REGRESSED (-4.3us, m190 lockstep
// regime: 8 synchronized waves starve the exp/pack waves) -> removed.
__global__ __launch_bounds__(512) void flash_attn_fused(
    const __hip_bfloat16* __restrict__ Vt,   // (B,H,72,32m,32c) prescaled
    const __hip_bfloat16* __restrict__ ZRt,  // (B,H,72,32n,32c)
    const __hip_bfloat16* __restrict__ Qtt,  // (B,H,72,32d,32n)
    __hip_bfloat16* __restrict__ Yt)         // (B,H,72,32m,32d) tiled
{
    __shared__ float Aw[8][32 * 36];   // per-wave Y^T partial, [m][dh] pitch 36
    __shared__ float Ls[8][64];        // per-wave per-lane lsum partials
    const int t = threadIdx.x;
    const int w = t >> 6, lane = t & 63;
    const int c = lane & 31, hi = lane >> 5;
    const int blk = blockIdx.x;
    const int bh = blk & 15, pair = blk >> 4;
    const int b = bh >> 3, h = bh & 7;
    const f32x16 zero16 = {0,0,0,0,0,0,0,0,0,0,0,0,0,0,0,0};

    const int lo = c * 32 + hi * 8;    // lane offset within a 1024-elem tile
    const size_t hb = (size_t)bh * kNT;

    // V fragments for both q-tiles of the pair
    bf16x8 vf[2][2];
    #pragma unroll
    for (int mt = 0; mt < 2; mt++) {
        const __hip_bfloat16* vb = Vt + (hb + pair * 2 + mt) * 1024 + lo;
        vf[mt][0] = *reinterpret_cast<const bf16x8*>(vb);
        vf[mt][1] = *reinterpret_cast<const bf16x8*>(vb + 16);
    }

    const __hip_bfloat16* zb = ZRt + (hb + w * 9) * 1024 + lo;   // walk +1024/iter
    const __hip_bfloat16* qb = Qtt + (hb + w * 9) * 1024 + lo;

    f32x16 acc[2] = {zero16, zero16};
    float lsum[2] = {0.f, 0.f};

    bf16x8 za0 = *reinterpret_cast<const bf16x8*>(zb);
    bf16x8 za1 = *reinterpret_cast<const bf16x8*>(zb + 16);
    bf16x8 qa0 = *reinterpret_cast<const bf16x8*>(qb);
    bf16x8 qa1 = *reinterpret_cast<const bf16x8*>(qb + 16);

    for (int it = 0; it < 9; ++it) {
        const int nx = (it < 8) ? (it + 1) * 1024 : 0;   // harmless wrap

        // prefetch next tile's fragments (contiguous 2KB slabs)
        bf16x8 za0n = *reinterpret_cast<const bf16x8*>(zb + nx);
        bf16x8 za1n = *reinterpret_cast<const bf16x8*>(zb + nx + 16);
        bf16x8 qa0n = *reinterpret_cast<const bf16x8*>(qb + nx);
        bf16x8 qa1n = *reinterpret_cast<const bf16x8*>(qb + nx + 16);

        #pragma unroll
        for (int mt = 0; mt < 2; mt++) {
            // QK^T for q-tile mt (KV regs shared across mt)
            f32x16 st = mfma32(za0, vf[mt][0], zero16);
            st = mfma32(za1, vf[mt][1], st);

            // raw exp2 (no max subtraction), tree sum
            float p[16];
            #pragma unroll
            for (int r = 0; r < 16; r++) p[r] = hexp2(st[r]);
            float s01 = (p[0] + p[1]) + (p[2] + p[3]);
            float s23 = (p[4] + p[5]) + (p[6] + p[7]);
            float s45 = (p[8] + p[9]) + (p[10] + p[11]);
            float s67 = (p[12] + p[13]) + (p[14] + p[15]);
            lsum[mt] += (s01 + s23) + (s45 + s67);

            // PV: two K=16 MFMAs; B-frags via cvt_pk + permlane32_swap
            #pragma unroll
            for (int kk = 0; kk < 2; kk++) {
                __hip_bfloat162 xw0 = __float22bfloat162_rn(make_float2(p[8*kk+0], p[8*kk+1]));
                __hip_bfloat162 xw1 = __float22bfloat162_rn(make_float2(p[8*kk+2], p[8*kk+3]));
                __hip_bfloat162 yw0 = __float22bfloat162_rn(make_float2(p[8*kk+4], p[8*kk+5]));
                __hip_bfloat162 yw1 = __float22bfloat162_rn(make_float2(p[8*kk+6], p[8*kk+7]));
                unsigned x0 = *reinterpret_cast<unsigned*>(&xw0);
                unsigned x1 = *reinterpret_cast<unsigned*>(&xw1);
                unsigned y0 = *reinterpret_cast<unsigned*>(&yw0);
                unsigned y1 = *reinterpret_cast<unsigned*>(&yw1);
                // vdst.hi <-> vsrc.lo: hi=0: {own x, partner x}; hi=1: {partner y, own y}
                asm("v_permlane32_swap_b32 %0, %1" : "+v"(x0), "+v"(y0));
                asm("v_permlane32_swap_b32 %0, %1" : "+v"(x1), "+v"(y1));
                union { unsigned u[4]; bf16x8 v; } bf;
                bf.u[0] = x0; bf.u[1] = x1; bf.u[2] = y0; bf.u[3] = y1;
                acc[mt] = mfma32(kk == 0 ? qa0 : qa1, bf.v, acc[mt]);
            }
        }

        za0 = za0n; za1 = za1n; qa0 = qa0n; qa1 = qa1n;
    }

    // epilogue: for each q-tile, stage partials + combine across the 8 waves
    #pragma unroll
    for (int mt = 0; mt < 2; mt++) {
        #pragma unroll
        for (int r = 0; r < 16; r++) {
            int dh = (r & 3) + 8 * (r >> 2) + 4 * hi;
            Aw[w][c * 36 + dh] = acc[mt][r];
        }
        Ls[w][lane] = lsum[mt];
        __syncthreads();

        if (t < 256) {   // 32 m-rows x 8 dh-groups of 4
            const int m = t & 31, dh0 = (t >> 5) * 4;
            float L = 0.f;
            #pragma unroll
            for (int w2 = 0; w2 < 8; w2++) L += Ls[w2][m] + Ls[w2][m + 32];
            f32x4 s4 = {0.f, 0.f, 0.f, 0.f};
            #pragma unroll
            for (int w2 = 0; w2 < 8; w2++)
                s4 = s4 + *reinterpret_cast<const f32x4*>(&Aw[w2][m * 36 + dh0]);
            float inv = 1.0f / L;
            union { uint2 u2; __hip_bfloat162 h2[2]; } o;
            o.h2[0] = __float22bfloat162_rn(make_float2(s4[0] * inv, s4[1] * inv));
            o.h2[1] = __float22bfloat162_rn(make_float2(s4[2] * inv, s4[3] * inv));
            // tiled write: Yt[b][h][tile=pair*2+mt][m][dh0..dh0+3]
            *reinterpret_cast<uint2*>(
                Yt + ((hb + pair * 2 + mt) * 32 + m) * 32 + dh0) = o.u2;
        }
        __syncthreads();   // WAR: next mt's staging must not race this combine
    }
}

// ---- output conv: dense Yt A-reads + dense tiled Wo B-reads ---------------
__global__ __launch_bounds__(64) void conv_out_gemm(const __hip_bfloat16* __restrict__ Yt,
                                                    const __hip_bfloat16* __restrict__ Wo,
                                                    float* __restrict__ out) {
    int t = threadIdx.x, li = t & 15, g = t >> 4;
    int m0 = blockIdx.x * 16, o0 = blockIdx.y * 64, b = blockIdx.z;
    const int mt = m0 >> 5, mmb = m0 & 31;

    bf16x8 a[8];
    #pragma unroll
    for (int kb = 0; kb < 8; kb++)
        a[kb] = *reinterpret_cast<const bf16x8*>(
            Yt + (((size_t)(b * kH + kb) * kNT + mt) * 32 + mmb + li) * 32 + g * 8);

    f32x4 acc[4] = {{0,0,0,0},{0,0,0,0},{0,0,0,0},{0,0,0,0}};
    const __hip_bfloat16* wp = Wo + (((size_t)(o0 >> 4) * 32 + g) * 16 + li) * 8;
    #pragma unroll
    for (int kb = 0; kb < 8; kb++) {
        #pragma unroll
        for (int ot = 0; ot < 4; ot++) {
            bf16x8 bw = *reinterpret_cast<const bf16x8*>(wp + ot * 4096 + kb * 512);
            acc[ot] = mfma16(a[kb], bw, acc[ot]);
        }
    }
    #pragma unroll
    for (int ot = 0; ot < 4; ot++) {
        int o = o0 + ot * 16 + li;
        *reinterpret_cast<f32x4*>(out + (size_t)(b * kC + o) * kM + m0 + 4 * g) = acc[ot];
    }
}

extern "C" void kernel_launch(void* const* d_in, const int* in_sizes, int n_in,
                              void* d_out, int out_size, void* d_ws, size_t ws_size,
                              hipStream_t stream) {
    const float* x     = (const float*)d_in[0];
    const float* gamma = (const float*)d_in[1];
    const float* beta  = (const float*)d_in[2];
    const float* rmean = (const float*)d_in[3];
    const float* rvar  = (const float*)d_in[4];
    const float* v_w   = (const float*)d_in[5];
    const float* z_w   = (const float*)d_in[6];
    const float* q_w   = (const float*)d_in[7];
    const float* o_w   = (const float*)d_in[8];
    float* out = (float*)d_out;

    char* wsb = (char*)d_ws;
    const size_t BMC = (size_t)kB * kM * kC;    // 1,179,648
    float* PEt     = (float*)(wsb + 4096);      // [pos][c], 49152 B -> ends 53248
    __hip_bfloat16* Wv16 = (__hip_bfloat16*)(wsb + 53248);   // tiled fragment order
    __hip_bfloat16* Wz16 = Wv16 + 65536;
    __hip_bfloat16* Wq16 = Wz16 + 65536;
    __hip_bfloat16* Wo16 = Wq16 + 65536;
    __hip_bfloat16* Xnt  = Wo16 + 65536;        // tiled fragment order
    __hip_bfloat16* Vt   = Xnt + BMC;           // tiled (B,H,72,32,32)
    __hip_bfloat16* Zb16 = Vt + BMC;            // (B,M,C)
    __hip_bfloat16* ZRt  = Zb16 + BMC;          // tiled
    __hip_bfloat16* Qtt  = ZRt + BMC;           // tiled
    __hip_bfloat16* Yt   = Qtt + BMC;           // tiled (B,H,72,32,32); ~14.7 MB

    prep_kernel<<<dim3(592), dim3(256), 0, stream>>>(
        x, gamma, beta, rmean, rvar, v_w, z_w, q_w, o_w,
        PEt, Wv16, Wz16, Wq16, Wo16, Xnt);
    conv_gemm<<<dim3(kM / 16, kC / 64, kB), dim3(64), 0, stream>>>(
        Xnt, Wv16, Wz16, Wq16, Vt, Zb16, Qtt);
    zr_kernel<<<dim3(kB * kM / 4), dim3(256), 0, stream>>>(Zb16, PEt, ZRt);
    flash_attn_fused<<<dim3((kNT / 2) * kH * kB), dim3(512), 0, stream>>>(Vt, ZRt, Qtt, Yt);
    conv_out_gemm<<<dim3(kM / 16, kC / 64, kB), dim3(64), 0, stream>>>(Yt, Wo16, out);
}